// Round 14
// baseline (458.956 us; speedup 1.0000x reference)
//
#include <hip/hip_runtime.h>
#include <float.h>
#include <math.h>

typedef __attribute__((ext_vector_type(8))) short bf16x8;
typedef __attribute__((ext_vector_type(4))) float f32x4;

// d_out float offsets (loss, quantized, perplexity, embedding, indices, encodings)
#define O_Q    1
#define O_PERP 8388609
#define O_EMB  8388610
#define O_IDX  9437186
#define O_ENC  9469954

// workspace float offsets: ETpk hi-limb image at byte 0 (2 MB)
#define W_CB   1048576
#define W_CNT  1052672
#define W_BS   1056768

#define MARGIN 0.4f

__device__ __forceinline__ unsigned short bf16_rne(float x) {
    unsigned u = __float_as_uint(x);
    unsigned r = u + 0x7FFFu + ((u >> 16) & 1u);
    return (unsigned short)(r >> 16);
}

__device__ __forceinline__ void gld_lds16(const void* g, void* l) {
    __builtin_amdgcn_global_load_lds(
        (const __attribute__((address_space(1))) unsigned int*)g,
        (__attribute__((address_space(3))) unsigned int*)l, 16, 0, 0);
}

__device__ __forceinline__ unsigned long long u64min(unsigned long long a, unsigned long long b){ return a < b ? a : b; }

__device__ __forceinline__ unsigned long long packkey(float s, int k) {
    unsigned u = __float_as_uint(s);
    u = (u & 0x80000000u) ? ~u : (u | 0x80000000u);
    return ((unsigned long long)u << 32) | (unsigned)k;
}
__device__ __forceinline__ float unpackf(unsigned long long key) {
    unsigned u = (unsigned)(key >> 32);
    u = (u & 0x80000000u) ? (u & 0x7FFFFFFFu) : ~u;
    return __uint_as_float(u);
}

// ---- E -> hi-limb image. chunk(kt,ks) 16KB = [codefrag16][64 units x 16B]
__global__ __launch_bounds__(256)
void k_prepE(const float* __restrict__ E, char* __restrict__ ETpk)
{
    int gid = blockIdx.x * 256 + threadIdx.x;   // 131072 = 4096 codes * 32 octets
    int code = gid >> 5, oct = gid & 31;
    const float* ep = E + (size_t)code * 256 + oct * 8;
    float4 a = *(const float4*)ep, c4 = *(const float4*)(ep + 4);
    float v[8] = {a.x, a.y, a.z, a.w, c4.x, c4.y, c4.z, c4.w};
    unsigned hw[8];
#pragma unroll
    for (int i = 0; i < 8; ++i) hw[i] = bf16_rne(v[i]);
    uint4 vh = {hw[0]|(hw[1]<<16), hw[2]|(hw[3]<<16), hw[4]|(hw[5]<<16), hw[6]|(hw[7]<<16)};
    int kt = code >> 8, cf = (code >> 4) & 15, row = code & 15;
    int dtv = oct >> 2, c = oct & 3;
    size_t chunk = (size_t)(kt * 8 + dtv) * 16384;
    *(uint4*)(ETpk + chunk + (size_t)(cf * 64 + (c*16 + row)) * 16) = vh;
}

// ---- 0.5*||e_k||^2 (fp32)
__global__ __launch_bounds__(256)
void k_cbias(const float* __restrict__ E, float* __restrict__ cb)
{
    const int tid = threadIdx.x;
    const int k   = blockIdx.x * 16 + (tid >> 4);
    const int ch  = tid & 15;
    const float* p = E + (size_t)k * 256 + ch * 16;
    float s = 0.f;
#pragma unroll
    for (int i = 0; i < 4; ++i) {
        float4 v = *(const float4*)(p + i * 4);
        s += v.x*v.x + v.y*v.y + v.z*v.z + v.w*v.w;
    }
#pragma unroll
    for (int m = 1; m < 16; m <<= 1) s += __shfl_xor(s, m, 64);
    if (ch == 0) cb[k] = 0.5f * s;
}

// ---- main: A-in-registers (2 M-fragments/wave), 2-combo (hh+lh) limb MFMA.
// grid 512, block 512 (8 waves 2Mx4N), tile 64 tok x 256 codes/kt.
// __launch_bounds__(512, 1): 256-VGPR cap -- A frags (128 VGPR) + acc + state
// fit in true VGPRs (round 13's (512,2) forced a 128 cap -> AGPR shuffling).
// Each B ds_read feeds 4 MFMAs (2 mi x 2 limbs).
// LDS 80KB: B-hi quad-buffered 4x16KB (staged 3 ahead) + cbh copy 16KB.
// Per rd: 2 gld_lds + 2 stores + 4 ds_read_b128 + 16 MFMA + vmcnt(10) + barrier.
__global__ __launch_bounds__(512, 1)
void k_main(const float* __restrict__ X, const char* __restrict__ ETpk,
            const float* __restrict__ cbh, const float* __restrict__ E,
            float* __restrict__ out, int* __restrict__ counts,
            float* __restrict__ bscore)
{
    extern __shared__ char lds[];
    char*  Bsl = lds;                    // 4 x 16 KB
    float* cbL = (float*)(lds + 65536);  // 16 KB (4096 floats)

    const int tid  = threadIdx.x;
    const int lane = tid & 63;
    const int wid  = tid >> 6;
    const int wm   = wid >> 2;        // 0..1 token half (32 tok each)
    const int wn   = wid & 3;         // 0..3 code quarter (64 codes)
    const int n0   = blockIdx.x * 64;
    const int b    = n0 >> 10;
    const int l0   = n0 & 1023;
    const size_t xbase = (size_t)b * 262144 + l0;
    float* encB = out + (size_t)O_ENC + (size_t)n0 * 4096;   // 8B-aligned float2 ok

    f32x4 acc[2][4];
#pragma unroll
    for (int mi = 0; mi < 2; ++mi)
#pragma unroll
        for (int nj = 0; nj < 4; ++nj) acc[mi][nj] = (f32x4){0.f,0.f,0.f,0.f};

    float s1[8], s2v[8];
    unsigned ipack[8];
#pragma unroll
    for (int s = 0; s < 8; ++s) { s1[s] = FLT_MAX; s2v[s] = FLT_MAX; ipack[s] = 0; }

    auto stageB = [&](int rnd, int slot) {
        const char* src = ETpk + (size_t)rnd * 16384;
        char* dst = Bsl + slot * 16384;
#pragma unroll
        for (int i = 0; i < 2; ++i)
            gld_lds16(src + i*8192 + tid*16, dst + i*8192 + tid*16);
    };

    // ---- prologue: stage B0..B2, cbh->LDS, A fragments (2 sets) into registers
    stageB(0, 0);
    stageB(1, 1);
    stageB(2, 2);
#pragma unroll
    for (int i = 0; i < 2; ++i)
        gld_lds16((const char*)cbh + i*8192 + tid*16, (char*)cbL + i*8192 + tid*16);
    bf16x8 ahf[2][8], alf[2][8];
#pragma unroll
    for (int mi = 0; mi < 2; ++mi) {
        const int t_l = wm * 32 + mi * 16 + (lane & 15);   // token row
        const int c_l = lane >> 4;                         // k-chunk 0..3
        const float* xp = X + xbase + t_l;
#pragma unroll
        for (int ks = 0; ks < 8; ++ks) {
            const int d0 = ks * 32 + c_l * 8;
            float v[8];
#pragma unroll
            for (int i = 0; i < 8; ++i) v[i] = xp[(size_t)(d0 + i) * 1024];
            unsigned hw[8], lw[8];
#pragma unroll
            for (int i = 0; i < 8; ++i) {
                unsigned short h = bf16_rne(v[i]);
                float hf = __uint_as_float((unsigned)h << 16);
                hw[i] = h; lw[i] = bf16_rne(v[i] - hf);
            }
            uint4 vh = {hw[0]|(hw[1]<<16), hw[2]|(hw[3]<<16), hw[4]|(hw[5]<<16), hw[6]|(hw[7]<<16)};
            uint4 vl = {lw[0]|(lw[1]<<16), lw[2]|(lw[3]<<16), lw[4]|(lw[5]<<16), lw[6]|(lw[7]<<16)};
            ahf[mi][ks] = *(bf16x8*)&vh;
            alf[mi][ks] = *(bf16x8*)&vl;
        }
    }
    __syncthreads();

    // ---- main loop: 16 kt x 8 ks (ks unrolled; slot = ks&3 static)
#pragma unroll 1
    for (int kt = 0; kt < 16; ++kt) {
#pragma unroll
        for (int ks = 0; ks < 8; ++ks) {
            const int rd = kt * 8 + ks;
            const int r3 = (rd + 3 < 128) ? rd + 3 : 127;
            stageB(r3, (ks + 3) & 3);
            {   // zero-fill 8KB of the one-hot region (2 float2/thread)
                float2 z2 = make_float2(0.f, 0.f);
                const int lin = rd * 2048 + tid * 2;
                *(float2*)(encB + (size_t)(lin >> 12) * 4096 + (lin & 4095)) = z2;
                const int lin2 = lin + 1024;
                *(float2*)(encB + (size_t)(lin2 >> 12) * 4096 + (lin2 & 4095)) = z2;
            }
            const char* Bp = Bsl + (ks & 3) * 16384;
#pragma unroll
            for (int nj = 0; nj < 4; ++nj) {
                bf16x8 bh = *(const bf16x8*)(Bp + (wn*4 + nj)*1024 + lane*16);
#pragma unroll
                for (int mi = 0; mi < 2; ++mi) {
                    acc[mi][nj] = __builtin_amdgcn_mfma_f32_16x16x32_bf16(ahf[mi][ks], bh, acc[mi][nj], 0, 0, 0);
                    acc[mi][nj] = __builtin_amdgcn_mfma_f32_16x16x32_bf16(alf[mi][ks], bh, acc[mi][nj], 0, 0, 0);
                }
            }
            // counted wait: newest 10 = rd's 4 + rd-1's 4 + rd-2's 2 stores;
            // forces rd-2's stage (for rd+1) complete; stores ride >=2 rds
            asm volatile("s_waitcnt vmcnt(10)" ::: "memory");
            __builtin_amdgcn_s_barrier();
        }
        // per-kt score + per-lane top2 (cbh from LDS: no vmem waits here)
        {
            const int cb0 = kt * 256 + wn * 64 + (lane & 15);
            float cbv[4];
#pragma unroll
            for (int nj = 0; nj < 4; ++nj) cbv[nj] = cbL[cb0 + nj * 16];
#pragma unroll
            for (int mi = 0; mi < 2; ++mi)
#pragma unroll
                for (int q = 0; q < 4; ++q) {
                    const int slot = mi * 4 + q;
#pragma unroll
                    for (int nj = 0; nj < 4; ++nj) {
                        float s = cbv[nj] - acc[mi][nj][q];
                        unsigned code = (unsigned)(cb0 + nj * 16);
                        if (s < s1[slot]) {
                            s2v[slot] = s1[slot];
                            ipack[slot] = ((ipack[slot] & 0xFFFFu) << 16) | code;
                            s1[slot] = s;
                        } else if (s < s2v[slot]) {
                            s2v[slot] = s;
                            ipack[slot] = (ipack[slot] & 0xFFFFu) | (code << 16);
                        }
                        acc[mi][nj][q] = 0.f;
                    }
                }
        }
    }

    asm volatile("s_waitcnt vmcnt(0)" ::: "memory");
    __syncthreads();   // drain zero-fill (zero -> one-hot ordering) + LDS reuse

    // ---- dump per-lane top2 keys: scr[t*64 + col] (64KB, reuses Bsl region)
    ulonglong2* scr = (ulonglong2*)lds;              // 64 tok x 64 cols x 16B
    int*   ids = (int*)(lds + 65536);                // reuses cbL region (done)
    float* wp  = (float*)(lds + 65536 + 256);
    {
        const int col = wn * 16 + (lane & 15);
#pragma unroll
        for (int mi = 0; mi < 2; ++mi)
#pragma unroll
            for (int q = 0; q < 4; ++q) {
                const int slot = mi * 4 + q;
                const int t = wm * 32 + mi * 16 + ((lane >> 4) << 2) + q;
                ulonglong2 kk;
                kk.x = packkey(s1[slot],  (int)(ipack[slot] & 0xFFFFu));
                kk.y = packkey(s2v[slot], (int)(ipack[slot] >> 16));
                scr[t * 64 + col] = kk;
            }
    }
    __syncthreads();

    // ---- per-token pool scan + conditional exact rescore
    if (tid < 64) {
        const ulonglong2* row = scr + tid * 64;
        unsigned long long m = 0xFFFFFFFFFFFFFFFFull;
#pragma unroll 1
        for (int i0 = 0; i0 < 64; ++i0) {
            int i = (tid + i0) & 63;            // staggered start
            m = u64min(m, row[i].x);            // key2 >= key1 always
        }
        int k = (int)(m & 0xFFFFull);
        const float thr = unpackf(m) + MARGIN;
        int cnt = 0;
#pragma unroll 1
        for (int i0 = 0; i0 < 64; ++i0) {
            int i = (tid + i0) & 63;
            ulonglong2 kk = row[i];
            cnt += (unpackf(kk.x) <= thr) + (unpackf(kk.y) <= thr);
        }
        if (cnt > 1) {
            float bd = FLT_MAX; int bi = 0x7FFFFFFF;
#pragma unroll 1
            for (int i0 = 0; i0 < 64; ++i0) {
                int i = (tid + i0) & 63;
                ulonglong2 kk = row[i];
#pragma unroll
                for (int h = 0; h < 2; ++h) {
                    unsigned long long key = h ? kk.y : kk.x;
                    if (unpackf(key) <= thr) {
                        int c = (int)(key & 0xFFFFull);
                        float d = 0.f;
                        for (int dd = 0; dd < 256; dd += 2) {
                            float xv0 = X[xbase + (size_t)dd * 1024 + tid];
                            float xv1 = X[xbase + (size_t)(dd + 1) * 1024 + tid];
                            float e0 = E[(size_t)c * 256 + dd];
                            float e1 = E[(size_t)c * 256 + dd + 1];
                            float f0 = xv0 - e0, f1 = xv1 - e1;
                            d += f0 * f0 + f1 * f1;
                        }
                        if (d < bd || (d == bd && c < bi)) { bd = d; bi = c; }
                    }
                }
            }
            k = bi;
        }
        ids[tid] = k;
        out[(size_t)O_IDX + n0 + tid] = (float)k;
        atomicAdd(&counts[k], 1);
        out[(size_t)O_ENC + (size_t)(n0 + tid) * 4096 + k] = 1.0f;
    }
    __syncthreads();

    // ---- fused quantize (STE arithmetic) + exact fp32 loss partial
    float dl = 0.f;
#pragma unroll 4
    for (int r = 0; r < 32; ++r) {
        int lin = r * 512 + tid;
        int d = lin >> 6, t = lin & 63;
        float q  = E[(size_t)ids[t] * 256 + d];
        float xv = X[xbase + (size_t)d * 1024 + t];
        out[(size_t)O_Q + xbase + (size_t)d * 1024 + t] = xv + (q - xv);
        float df = q - xv;
        dl += df * df;
    }
#pragma unroll
    for (int m = 1; m < 64; m <<= 1) dl += __shfl_xor(dl, m, 64);
    if (lane == 0) wp[wid] = dl;
    __syncthreads();
    if (tid == 0) {
        float s = 0.f;
#pragma unroll
        for (int w = 0; w < 8; ++w) s += wp[w];
        bscore[blockIdx.x] = s;
    }
}

// ---- scalars: loss + perplexity (512 block partials)
__global__ __launch_bounds__(256)
void k_final(const float* __restrict__ bscore, const int* __restrict__ counts,
             float* __restrict__ out)
{
    const int tid = threadIdx.x;
    float s = bscore[tid] + bscore[tid + 256];
    float h = 0.f;
#pragma unroll
    for (int i = 0; i < 16; ++i) {
        float p = (float)counts[tid * 16 + i] * (1.0f / 32768.f);
        h += p * logf(p + 1e-10f);
    }
#pragma unroll
    for (int m = 1; m < 64; m <<= 1) {
        s += __shfl_xor(s, m, 64);
        h += __shfl_xor(h, m, 64);
    }
    __shared__ float rs[4], rh[4];
    if ((tid & 63) == 0) { rs[tid >> 6] = s; rh[tid >> 6] = h; }
    __syncthreads();
    if (tid == 0) {
        float S = rs[0] + rs[1] + rs[2] + rs[3];
        float H = rh[0] + rh[1] + rh[2] + rh[3];
        out[0]      = 0.25f * S / 8388608.f;
        out[O_PERP] = expf(-H);
    }
}

extern "C" void kernel_launch(void* const* d_in, const int* in_sizes, int n_in,
                              void* d_out, int out_size, void* d_ws, size_t ws_size,
                              hipStream_t stream)
{
    (void)in_sizes; (void)n_in; (void)out_size; (void)ws_size;
    const float* X = (const float*)d_in[0];
    const float* E = (const float*)d_in[1];
    float* out = (float*)d_out;
    float* ws  = (float*)d_ws;
    char*  ETpk   = (char*)ws;
    float* cbh    = ws + W_CB;
    int*   counts = (int*)(ws + W_CNT);
    float* bsc    = ws + W_BS;

    hipMemsetAsync(counts, 0, 4096 * sizeof(int), stream);
    k_prepE<<<512, 256, 0, stream>>>(E, ETpk);
    k_cbias<<<256, 256, 0, stream>>>(E, cbh);
    hipFuncSetAttribute(reinterpret_cast<const void*>(&k_main),
                        hipFuncAttributeMaxDynamicSharedMemorySize, 81920);
    k_main <<<512, 512, 81920, stream>>>(X, ETpk, cbh, E, out, counts, bsc);
    k_final<<<1, 256, 0, stream>>>(bsc, counts, out);
    hipMemcpyAsync(out + O_EMB, E, (size_t)4096 * 256 * sizeof(float),
                   hipMemcpyDeviceToDevice, stream);
}

// Round 15
// 388.158 us; speedup vs baseline: 1.1824x; 1.1824x over previous
//
#include <hip/hip_runtime.h>
#include <float.h>
#include <math.h>

typedef __attribute__((ext_vector_type(8))) short bf16x8;
typedef __attribute__((ext_vector_type(4))) float f32x4;

// d_out float offsets (loss, quantized, perplexity, embedding, indices, encodings)
#define O_Q    1
#define O_PERP 8388609
#define O_EMB  8388610
#define O_IDX  9437186
#define O_ENC  9469954

// workspace float offsets: ETpk hi-limb image at byte 0 (2 MB)
#define W_CB   1048576
#define W_CNT  1052672
#define W_BS   1056768

#define MARGIN 0.4f

__device__ __forceinline__ unsigned short bf16_rne(float x) {
    unsigned u = __float_as_uint(x);
    unsigned r = u + 0x7FFFu + ((u >> 16) & 1u);
    return (unsigned short)(r >> 16);
}

__device__ __forceinline__ void gld_lds16(const void* g, void* l) {
    __builtin_amdgcn_global_load_lds(
        (const __attribute__((address_space(1))) unsigned int*)g,
        (__attribute__((address_space(3))) unsigned int*)l, 16, 0, 0);
}

__device__ __forceinline__ unsigned long long u64min(unsigned long long a, unsigned long long b){ return a < b ? a : b; }

__device__ __forceinline__ unsigned long long packkey(float s, int k) {
    unsigned u = __float_as_uint(s);
    u = (u & 0x80000000u) ? ~u : (u | 0x80000000u);
    return ((unsigned long long)u << 32) | (unsigned)k;
}
__device__ __forceinline__ float unpackf(unsigned long long key) {
    unsigned u = (unsigned)(key >> 32);
    u = (u & 0x80000000u) ? (u & 0x7FFFFFFFu) : ~u;
    return __uint_as_float(u);
}

// ---- E -> hi-limb image. chunk(kt,ks) 16KB = [codefrag16][64 units x 16B]
__global__ __launch_bounds__(256)
void k_prepE(const float* __restrict__ E, char* __restrict__ ETpk)
{
    int gid = blockIdx.x * 256 + threadIdx.x;   // 131072 = 4096 codes * 32 octets
    int code = gid >> 5, oct = gid & 31;
    const float* ep = E + (size_t)code * 256 + oct * 8;
    float4 a = *(const float4*)ep, c4 = *(const float4*)(ep + 4);
    float v[8] = {a.x, a.y, a.z, a.w, c4.x, c4.y, c4.z, c4.w};
    unsigned hw[8];
#pragma unroll
    for (int i = 0; i < 8; ++i) hw[i] = bf16_rne(v[i]);
    uint4 vh = {hw[0]|(hw[1]<<16), hw[2]|(hw[3]<<16), hw[4]|(hw[5]<<16), hw[6]|(hw[7]<<16)};
    int kt = code >> 8, cf = (code >> 4) & 15, row = code & 15;
    int dtv = oct >> 2, c = oct & 3;
    size_t chunk = (size_t)(kt * 8 + dtv) * 16384;
    *(uint4*)(ETpk + chunk + (size_t)(cf * 64 + (c*16 + row)) * 16) = vh;
}

// ---- 0.5*||e_k||^2 (fp32)
__global__ __launch_bounds__(256)
void k_cbias(const float* __restrict__ E, float* __restrict__ cb)
{
    const int tid = threadIdx.x;
    const int k   = blockIdx.x * 16 + (tid >> 4);
    const int ch  = tid & 15;
    const float* p = E + (size_t)k * 256 + ch * 16;
    float s = 0.f;
#pragma unroll
    for (int i = 0; i < 4; ++i) {
        float4 v = *(const float4*)(p + i * 4);
        s += v.x*v.x + v.y*v.y + v.z*v.z + v.w*v.w;
    }
#pragma unroll
    for (int m = 1; m < 16; m <<= 1) s += __shfl_xor(s, m, 64);
    if (ch == 0) cb[k] = 0.5f * s;
}

// ---- main: round-10 base (A-in-regs 2-combo hh+lh, per-lane top2 + pool rescore)
// with 2 K-steps per barrier: 64 sync quanta instead of 128.
// grid 1024, block 512 (8 waves 2Mx4N), tile 32 tok x 256 codes/kt.
// LDS 64KB: B-hi 4 slots x 16KB, slot = rd&3, staged 2 rds ahead.
// Per quantum: stage 2 chunks -> 2 zero-fill stores -> 8 ds_read + 16 MFMA
//              -> vmcnt(2) (stores ride; stage forced done) -> barrier.
__global__ __launch_bounds__(512, 4)
void k_main(const float* __restrict__ X, const char* __restrict__ ETpk,
            const float* __restrict__ cbh, const float* __restrict__ E,
            float* __restrict__ out, int* __restrict__ counts,
            float* __restrict__ bscore)
{
    extern __shared__ char lds[];
    char* Bsl = lds;                  // 4 x 16 KB

    const int tid  = threadIdx.x;
    const int lane = tid & 63;
    const int wid  = tid >> 6;
    const int wm   = wid >> 2;        // 0..1 token half (16 tok)
    const int wn   = wid & 3;         // 0..3 code quarter (64 codes)
    const int n0   = blockIdx.x * 32;
    const int b    = n0 >> 10;
    const int l0   = n0 & 1023;
    const size_t xbase = (size_t)b * 262144 + l0;
    float* encB = out + (size_t)O_ENC + (size_t)n0 * 4096;   // 8B-aligned float2 ok

    f32x4 acc[4];
#pragma unroll
    for (int nj = 0; nj < 4; ++nj) acc[nj] = (f32x4){0.f,0.f,0.f,0.f};

    float s1[4], s2v[4];
    unsigned ipack[4];
#pragma unroll
    for (int s = 0; s < 4; ++s) { s1[s] = FLT_MAX; s2v[s] = FLT_MAX; ipack[s] = 0; }

    auto stageB = [&](int rnd, int slot) {
        const char* src = ETpk + (size_t)rnd * 16384;
        char* dst = Bsl + slot * 16384;
#pragma unroll
        for (int i = 0; i < 2; ++i)
            gld_lds16(src + i*8192 + tid*16, dst + i*8192 + tid*16);
    };

    // ---- prologue: stage B0,B1; load+split A fragments into registers
    stageB(0, 0);
    stageB(1, 1);
    bf16x8 ahf[8], alf[8];
    {
        const int t_l = wm * 16 + (lane & 15);     // token row of this lane
        const int c_l = lane >> 4;                 // k-chunk 0..3
        const float* xp = X + xbase + t_l;
#pragma unroll
        for (int ks = 0; ks < 8; ++ks) {
            const int d0 = ks * 32 + c_l * 8;
            float v[8];
#pragma unroll
            for (int i = 0; i < 8; ++i) v[i] = xp[(size_t)(d0 + i) * 1024];
            unsigned hw[8], lw[8];
#pragma unroll
            for (int i = 0; i < 8; ++i) {
                unsigned short h = bf16_rne(v[i]);
                float hf = __uint_as_float((unsigned)h << 16);
                hw[i] = h; lw[i] = bf16_rne(v[i] - hf);
            }
            uint4 vh = {hw[0]|(hw[1]<<16), hw[2]|(hw[3]<<16), hw[4]|(hw[5]<<16), hw[6]|(hw[7]<<16)};
            uint4 vl = {lw[0]|(lw[1]<<16), lw[2]|(lw[3]<<16), lw[4]|(lw[5]<<16), lw[6]|(lw[7]<<16)};
            ahf[ks] = *(bf16x8*)&vh;
            alf[ks] = *(bf16x8*)&vl;
        }
    }
    __syncthreads();

    // ---- main loop: 16 kt x 4 quanta (2 rds each)
#pragma unroll 1
    for (int kt = 0; kt < 16; ++kt) {
#pragma unroll
        for (int qq = 0; qq < 4; ++qq) {
            const int r0 = kt * 8 + qq * 2;
            const int r1 = r0 + 1;
            const int ks0 = qq * 2, ks1 = qq * 2 + 1;
            // stage rd+2 pair (slots disjoint from the two being read)
            stageB(r0 + 2 < 128 ? r0 + 2 : 127, (r0 + 2) & 3);
            stageB(r1 + 2 < 128 ? r1 + 2 : 127, (r1 + 2) & 3);
            {   // zero-fill 8KB of the one-hot region (2 float2/thread)
                float2 z2 = make_float2(0.f, 0.f);
                const int lin0 = r0 * 1024 + tid * 2;
                *(float2*)(encB + (size_t)(lin0 >> 12) * 4096 + (lin0 & 4095)) = z2;
                const int lin1 = r1 * 1024 + tid * 2;
                *(float2*)(encB + (size_t)(lin1 >> 12) * 4096 + (lin1 & 4095)) = z2;
            }
            // compute rd r0
            {
                const char* Bp = Bsl + (r0 & 3) * 16384;
#pragma unroll
                for (int nj = 0; nj < 4; ++nj) {
                    bf16x8 bh = *(const bf16x8*)(Bp + (wn*4 + nj)*1024 + lane*16);
                    acc[nj] = __builtin_amdgcn_mfma_f32_16x16x32_bf16(ahf[ks0], bh, acc[nj], 0, 0, 0);
                    acc[nj] = __builtin_amdgcn_mfma_f32_16x16x32_bf16(alf[ks0], bh, acc[nj], 0, 0, 0);
                }
            }
            // compute rd r1
            {
                const char* Bp = Bsl + (r1 & 3) * 16384;
#pragma unroll
                for (int nj = 0; nj < 4; ++nj) {
                    bf16x8 bh = *(const bf16x8*)(Bp + (wn*4 + nj)*1024 + lane*16);
                    acc[nj] = __builtin_amdgcn_mfma_f32_16x16x32_bf16(ahf[ks1], bh, acc[nj], 0, 0, 0);
                    acc[nj] = __builtin_amdgcn_mfma_f32_16x16x32_bf16(alf[ks1], bh, acc[nj], 0, 0, 0);
                }
            }
            // per-kt score + per-lane top2 on the last quantum of this kt
            if (qq == 3) {
                const int cb0 = kt * 256 + wn * 64 + (lane & 15);
                float cbv[4];
#pragma unroll
                for (int nj = 0; nj < 4; ++nj) cbv[nj] = cbh[cb0 + nj * 16];
#pragma unroll
                for (int q = 0; q < 4; ++q)
#pragma unroll
                    for (int nj = 0; nj < 4; ++nj) {
                        float s = cbv[nj] - acc[nj][q];
                        unsigned code = (unsigned)(cb0 + nj * 16);
                        if (s < s1[q]) {
                            s2v[q] = s1[q];
                            ipack[q] = ((ipack[q] & 0xFFFFu) << 16) | code;
                            s1[q] = s;
                        } else if (s < s2v[q]) {
                            s2v[q] = s;
                            ipack[q] = (ipack[q] & 0xFFFFu) | (code << 16);
                        }
                        acc[nj][q] = 0.f;
                    }
            }
            // counted wait: newest 2 = this quantum's stores (ride across);
            // this quantum's stage forced complete for next quantum's compute
            asm volatile("s_waitcnt vmcnt(2)" ::: "memory");
            __builtin_amdgcn_s_barrier();
        }
    }

    asm volatile("s_waitcnt vmcnt(0)" ::: "memory");
    __syncthreads();   // drain zero-fill stores (zero -> one-hot ordering) + LDS reuse

    // ---- dump per-lane top2 keys: scr[(t*64 + col)] = {key1, key2}
    ulonglong2* scr = (ulonglong2*)lds;          // 32 tok x 64 cols x 16B = 32 KB
    int*   ids = (int*)(lds + 32768);
    float* wp  = (float*)(lds + 32768 + 128);
    {
        const int col = wn * 16 + (lane & 15);
#pragma unroll
        for (int q = 0; q < 4; ++q) {
            const int t = wm * 16 + ((lane >> 4) << 2) + q;
            ulonglong2 kk;
            kk.x = packkey(s1[q],  (int)(ipack[q] & 0xFFFFu));
            kk.y = packkey(s2v[q], (int)(ipack[q] >> 16));
            scr[t * 64 + col] = kk;
        }
    }
    __syncthreads();

    // ---- per-token pool scan + conditional exact rescore
    if (tid < 32) {
        const ulonglong2* row = scr + tid * 64;
        unsigned long long m = 0xFFFFFFFFFFFFFFFFull;
#pragma unroll 1
        for (int i0 = 0; i0 < 64; ++i0) {       // staggered start: fewer bank conflicts
            int i = (2 * tid + i0) & 63;
            m = u64min(m, row[i].x);            // key2 >= key1 always
        }
        int k = (int)(m & 0xFFFFull);
        const float thr = unpackf(m) + MARGIN;
        int cnt = 0;
#pragma unroll 1
        for (int i0 = 0; i0 < 64; ++i0) {
            int i = (2 * tid + i0) & 63;
            ulonglong2 kk = row[i];
            cnt += (unpackf(kk.x) <= thr) + (unpackf(kk.y) <= thr);
        }
        if (cnt > 1) {
            float bd = FLT_MAX; int bi = 0x7FFFFFFF;
#pragma unroll 1
            for (int i0 = 0; i0 < 64; ++i0) {
                int i = (2 * tid + i0) & 63;
                ulonglong2 kk = row[i];
#pragma unroll
                for (int h = 0; h < 2; ++h) {
                    unsigned long long key = h ? kk.y : kk.x;
                    if (unpackf(key) <= thr) {
                        int c = (int)(key & 0xFFFFull);
                        float d = 0.f;
                        for (int dd = 0; dd < 256; dd += 2) {
                            float xv0 = X[xbase + (size_t)dd * 1024 + tid];
                            float xv1 = X[xbase + (size_t)(dd + 1) * 1024 + tid];
                            float e0 = E[(size_t)c * 256 + dd];
                            float e1 = E[(size_t)c * 256 + dd + 1];
                            float f0 = xv0 - e0, f1 = xv1 - e1;
                            d += f0 * f0 + f1 * f1;
                        }
                        if (d < bd || (d == bd && c < bi)) { bd = d; bi = c; }
                    }
                }
            }
            k = bi;
        }
        ids[tid] = k;
        out[(size_t)O_IDX + n0 + tid] = (float)k;
        atomicAdd(&counts[k], 1);
        out[(size_t)O_ENC + (size_t)(n0 + tid) * 4096 + k] = 1.0f;
    }
    __syncthreads();

    // ---- fused quantize (STE arithmetic) + exact fp32 loss partial
    float dl = 0.f;
#pragma unroll 4
    for (int r = 0; r < 16; ++r) {
        int lin = r * 512 + tid;
        int d = lin >> 5, t = lin & 31;
        float q  = E[(size_t)ids[t] * 256 + d];
        float xv = X[xbase + (size_t)d * 1024 + t];
        out[(size_t)O_Q + xbase + (size_t)d * 1024 + t] = xv + (q - xv);
        float df = q - xv;
        dl += df * df;
    }
#pragma unroll
    for (int m = 1; m < 64; m <<= 1) dl += __shfl_xor(dl, m, 64);
    if (lane == 0) wp[wid] = dl;
    __syncthreads();
    if (tid == 0) {
        float s = 0.f;
#pragma unroll
        for (int w = 0; w < 8; ++w) s += wp[w];
        bscore[blockIdx.x] = s;
    }
}

// ---- scalars: loss + perplexity (1024 block partials)
__global__ __launch_bounds__(256)
void k_final(const float* __restrict__ bscore, const int* __restrict__ counts,
             float* __restrict__ out)
{
    const int tid = threadIdx.x;
    float s = bscore[tid] + bscore[tid + 256] + bscore[tid + 512] + bscore[tid + 768];
    float h = 0.f;
#pragma unroll
    for (int i = 0; i < 16; ++i) {
        float p = (float)counts[tid * 16 + i] * (1.0f / 32768.f);
        h += p * logf(p + 1e-10f);
    }
#pragma unroll
    for (int m = 1; m < 64; m <<= 1) {
        s += __shfl_xor(s, m, 64);
        h += __shfl_xor(h, m, 64);
    }
    __shared__ float rs[4], rh[4];
    if ((tid & 63) == 0) { rs[tid >> 6] = s; rh[tid >> 6] = h; }
    __syncthreads();
    if (tid == 0) {
        float S = rs[0] + rs[1] + rs[2] + rs[3];
        float H = rh[0] + rh[1] + rh[2] + rh[3];
        out[0]      = 0.25f * S / 8388608.f;
        out[O_PERP] = expf(-H);
    }
}

extern "C" void kernel_launch(void* const* d_in, const int* in_sizes, int n_in,
                              void* d_out, int out_size, void* d_ws, size_t ws_size,
                              hipStream_t stream)
{
    (void)in_sizes; (void)n_in; (void)out_size; (void)ws_size;
    const float* X = (const float*)d_in[0];
    const float* E = (const float*)d_in[1];
    float* out = (float*)d_out;
    float* ws  = (float*)d_ws;
    char*  ETpk   = (char*)ws;
    float* cbh    = ws + W_CB;
    int*   counts = (int*)(ws + W_CNT);
    float* bsc    = ws + W_BS;

    hipMemsetAsync(counts, 0, 4096 * sizeof(int), stream);
    k_prepE<<<512, 256, 0, stream>>>(E, ETpk);
    k_cbias<<<256, 256, 0, stream>>>(E, cbh);
    hipFuncSetAttribute(reinterpret_cast<const void*>(&k_main),
                        hipFuncAttributeMaxDynamicSharedMemorySize, 65536);
    k_main <<<1024, 512, 65536, stream>>>(X, ETpk, cbh, E, out, counts, bsc);
    k_final<<<1, 256, 0, stream>>>(bsc, counts, out);
    hipMemcpyAsync(out + O_EMB, E, (size_t)4096 * 256 * sizeof(float),
                   hipMemcpyDeviceToDevice, stream);
}